// Round 2
// baseline (2112.666 us; speedup 1.0000x reference)
//
#include <hip/hip_runtime.h>
#include <hip/hip_bf16.h>
#include <math.h>

// Persistent intermediates (static device arrays; d_ws not needed)
__device__ float g_feat[9216 * 400];   // [0,1024): img feats; [1024,9216): ref feats (n*8+s)
__device__ float g_xall[9216 * 12];    // feat @ Wf^T + bf for ALL 9216 rows
__device__ float g_grad[1024 * 120];   // feat_img @ Wg^T + bg

// ---------------------------------------------------------------------------
// Kernel 1: LeNet trunk, one block (256 thr) per image.
// LDS layout (floats), alias-packed to 11032 floats = 44.1 KB -> 3 blocks/CU:
//   [0,3456)      s_in  (3 x 32 x 36-padded)   | aliased by s_p1 (6 x 14 x 16)
//   [3456,8160)   s_c1  (6 x 28 x 28)          | aliased by s_c2 (16 x 10 x 12)
//   [8160,8610)   s_w1; [8610,11010) s_w2; [11010,11016) s_b1; [11016,11032) s_b2
// ---------------------------------------------------------------------------
__global__ __launch_bounds__(256, 3) void lenet_kernel(
    const float* __restrict__ img, const float* __restrict__ train,
    const int* __restrict__ refs,
    const float* __restrict__ w1, const float* __restrict__ b1,
    const float* __restrict__ w2, const float* __restrict__ b2)
{
    __shared__ __align__(16) float smem[11032];
    float* s_in = smem;            // stride: ic*1152 + y*36 + x
    float* s_p1 = smem;            // stride: ic*224 + y*16 + x
    float* s_c1 = smem + 3456;     // stride: oc*784 + y*28 + x
    float* s_c2 = smem + 3456;     // stride: oc*120 + y*12 + x
    float* s_w1 = smem + 8160;
    float* s_w2 = smem + 8610;
    float* s_b1 = smem + 11010;
    float* s_b2 = smem + 11016;

    const int blk = blockIdx.x;
    const int tid = threadIdx.x;
    const int wid = tid >> 6, lane = tid & 63;

    // ---- stage input image (padded rows) + weights ----
    const float* src = (blk < 1024)
        ? (img + (size_t)blk * 3072)
        : (train + (size_t)refs[blk - 1024] * 3072);
    const float4* src4 = (const float4*)src;
    for (int i = tid; i < 768; i += 256) {
        const float4 v = src4[i];
        const int r = i >> 3, ch = i & 7;          // row 0..95, chunk 0..7
        const int ic = r >> 5, yy = r & 31;
        *(float4*)&s_in[ic * 1152 + yy * 36 + ch * 4] = v;
    }
    for (int i = tid; i < 450;  i += 256) s_w1[i] = w1[i];
    for (int i = tid; i < 2400; i += 256) s_w2[i] = w2[i];
    if (tid < 6)  s_b1[tid] = b1[tid];
    if (tid < 16) s_b2[tid] = b2[tid];
    __syncthreads();

    // ---- conv1: wave handles one 32x32(padded) oc plane; lane = 4x4 tile ----
    {
        const int ox4 = (lane & 7) * 4;
        const int oy0 = (lane >> 3) * 4;
        for (int oc = wid; oc < 6; oc += 4) {
            float wreg[25];
            float acc[4][4];
            const float bias = s_b1[oc];
            #pragma unroll
            for (int r = 0; r < 4; ++r)
                #pragma unroll
                for (int j = 0; j < 4; ++j) acc[r][j] = bias;
            for (int ic = 0; ic < 3; ++ic) {
                #pragma unroll
                for (int q = 0; q < 25; ++q) wreg[q] = s_w1[oc * 75 + ic * 25 + q];
                #pragma unroll
                for (int dy = 0; dy < 8; ++dy) {
                    int y = oy0 + dy; y = y > 31 ? 31 : y;
                    const float4 fa = *(const float4*)&s_in[ic * 1152 + y * 36 + ox4];
                    const float4 fb = *(const float4*)&s_in[ic * 1152 + y * 36 + ox4 + 4];
                    const float in[8] = {fa.x, fa.y, fa.z, fa.w, fb.x, fb.y, fb.z, fb.w};
                    #pragma unroll
                    for (int r = 0; r < 4; ++r) {
                        const int ky = dy - r;
                        if (ky >= 0 && ky < 5) {
                            #pragma unroll
                            for (int kx = 0; kx < 5; ++kx) {
                                const float w = wreg[ky * 5 + kx];
                                acc[r][0] += in[0 + kx] * w;
                                acc[r][1] += in[1 + kx] * w;
                                acc[r][2] += in[2 + kx] * w;
                                acc[r][3] += in[3 + kx] * w;
                            }
                        }
                    }
                }
            }
            if (((lane & 7) < 7) && ((lane >> 3) < 7)) {
                #pragma unroll
                for (int r = 0; r < 4; ++r)
                    *(float4*)&s_c1[oc * 784 + (oy0 + r) * 28 + ox4] =
                        make_float4(acc[r][0], acc[r][1], acc[r][2], acc[r][3]);
            }
        }
    }
    __syncthreads();

    // ---- relu + pool1 -> s_p1 (6 x 14 x 16pad), aliases s_in ----
    for (int t = tid; t < 1176; t += 256) {
        const int oc = t / 196, rem = t % 196, py = rem / 14, px = rem % 14;
        const float* p = &s_c1[oc * 784 + py * 56 + px * 2];
        const float m = fmaxf(fmaxf(p[0], p[1]), fmaxf(p[28], p[29]));
        s_p1[oc * 224 + py * 16 + px] = fmaxf(m, 0.0f);
    }
    __syncthreads();

    // ---- conv2: 16 oc x 9 combos = 144 lane-tasks; lane = 4x4 tile ----
    if (tid < 144) {
        const int oc = tid / 9, combo = tid % 9;
        const int ox4 = (combo % 3) * 4;
        const int oy0 = (combo / 3) * 4;
        float wreg[25];
        float acc[4][4];
        const float bias = s_b2[oc];
        #pragma unroll
        for (int r = 0; r < 4; ++r)
            #pragma unroll
            for (int j = 0; j < 4; ++j) acc[r][j] = bias;
        for (int ic = 0; ic < 6; ++ic) {
            #pragma unroll
            for (int q = 0; q < 25; ++q) wreg[q] = s_w2[oc * 150 + ic * 25 + q];
            #pragma unroll
            for (int dy = 0; dy < 8; ++dy) {
                int y = oy0 + dy; y = y > 13 ? 13 : y;
                const float4 fa = *(const float4*)&s_p1[ic * 224 + y * 16 + ox4];
                const float4 fb = *(const float4*)&s_p1[ic * 224 + y * 16 + ox4 + 4];
                const float4 fc = *(const float4*)&s_p1[ic * 224 + y * 16 + ox4 + 8];
                const float in[12] = {fa.x, fa.y, fa.z, fa.w, fb.x, fb.y, fb.z, fb.w,
                                      fc.x, fc.y, fc.z, fc.w};
                #pragma unroll
                for (int r = 0; r < 4; ++r) {
                    const int ky = dy - r;
                    if (ky >= 0 && ky < 5) {
                        #pragma unroll
                        for (int kx = 0; kx < 5; ++kx) {
                            const float w = wreg[ky * 5 + kx];
                            acc[r][0] += in[0 + kx] * w;
                            acc[r][1] += in[1 + kx] * w;
                            acc[r][2] += in[2 + kx] * w;
                            acc[r][3] += in[3 + kx] * w;
                        }
                    }
                }
            }
        }
        #pragma unroll
        for (int r = 0; r < 4; ++r) {
            if (oy0 + r < 10)
                *(float4*)&s_c2[oc * 120 + (oy0 + r) * 12 + ox4] =
                    make_float4(acc[r][0], acc[r][1], acc[r][2], acc[r][3]);
        }
    }
    __syncthreads();

    // ---- relu + pool2 -> feature vector (NCHW flatten order) ----
    float* fo = g_feat + (size_t)blk * 400;
    for (int t = tid; t < 400; t += 256) {
        const int oc = t / 25, rem = t % 25, py = rem / 5, px = rem % 5;
        const float* p = &s_c2[oc * 120 + py * 24 + px * 2];
        const float m = fmaxf(fmaxf(p[0], p[1]), fmaxf(p[12], p[13]));
        fo[t] = fmaxf(m, 0.0f);
    }
}

// ---------------------------------------------------------------------------
// Kernel 2: xall = g_feat @ Wf^T + bf  (9216 x 12). Lane = row; weights via
// wave-uniform scalar loads (SGPR operands).
// ---------------------------------------------------------------------------
__global__ __launch_bounds__(256) void xall_kernel(
    const float* __restrict__ Wf, const float* __restrict__ bf)
{
    const int row = blockIdx.x * 256 + threadIdx.x;
    float acc[12];
    #pragma unroll
    for (int c = 0; c < 12; ++c) acc[c] = 0.0f;
    const float* f = g_feat + (size_t)row * 400;
    for (int k = 0; k < 400; k += 4) {
        const float4 f4 = *(const float4*)&f[k];
        #pragma unroll
        for (int c = 0; c < 12; ++c) {
            const float* w = Wf + c * 400 + k;
            acc[c] += f4.x * w[0] + f4.y * w[1] + f4.z * w[2] + f4.w * w[3];
        }
    }
    #pragma unroll
    for (int c = 0; c < 12; ++c) g_xall[(size_t)row * 12 + c] = acc[c] + bf[c];
}

// ---------------------------------------------------------------------------
// Kernel 3: grad = g_feat[0:1024] @ Wg^T + bg  (1024 x 120), col-split x4.
// ---------------------------------------------------------------------------
__global__ __launch_bounds__(64) void grad_kernel(
    const float* __restrict__ Wg, const float* __restrict__ bg)
{
    const int rb = blockIdx.x & 15, cb = blockIdx.x >> 4;
    const int row = rb * 64 + threadIdx.x;
    const int c0 = cb * 30;
    float acc[30];
    #pragma unroll
    for (int c = 0; c < 30; ++c) acc[c] = 0.0f;
    const float* f = g_feat + (size_t)row * 400;
    for (int k = 0; k < 400; k += 4) {
        const float4 f4 = *(const float4*)&f[k];
        #pragma unroll
        for (int c = 0; c < 30; ++c) {
            const float* w = Wg + (size_t)(c0 + c) * 400 + k;
            acc[c] += f4.x * w[0] + f4.y * w[1] + f4.z * w[2] + f4.w * w[3];
        }
    }
    #pragma unroll
    for (int c = 0; c < 30; ++c)
        g_grad[(size_t)row * 120 + c0 + c] = acc[c] + bg[c0 + c];
}

// ---------------------------------------------------------------------------
// Kernel 4: combine. Lane = n. Factors the einsum:
// out = bm + (sum_s d_s mem[r_s]) @ Wm^T + (sum_s d_s diff_s) @ grad
// ---------------------------------------------------------------------------
__global__ __launch_bounds__(64) void combine_kernel(
    const float* __restrict__ mem, const float* __restrict__ Wm,
    const float* __restrict__ bm, const int* __restrict__ refs,
    float* __restrict__ out)
{
    const int n = blockIdx.x * 64 + threadIdx.x;
    float x[12];
    #pragma unroll
    for (int q = 0; q < 3; ++q) {
        const float4 v = *(const float4*)&g_xall[(size_t)n * 12 + q * 4];
        x[q * 4 + 0] = v.x; x[q * 4 + 1] = v.y; x[q * 4 + 2] = v.z; x[q * 4 + 3] = v.w;
    }
    float d[8];
    #pragma unroll
    for (int s = 0; s < 8; ++s) {
        const float* rx = &g_xall[(size_t)(1024 + n * 8 + s) * 12];
        float nn = 0.0f;
        #pragma unroll
        for (int h = 0; h < 12; ++h) { const float df = x[h] - rx[h]; nn += df * df; }
        d[s] = -sqrtf(nn);
    }
    float mx = d[0];
    #pragma unroll
    for (int s = 1; s < 8; ++s) mx = fmaxf(mx, d[s]);
    float tot = 0.0f;
    #pragma unroll
    for (int s = 0; s < 8; ++s) { d[s] = expf(d[s] - mx); tot += d[s]; }
    const float inv = 1.0f / tot;
    #pragma unroll
    for (int s = 0; s < 8; ++s) d[s] *= inv;

    float wdiff[12], wmem[10];
    #pragma unroll
    for (int h = 0; h < 12; ++h) wdiff[h] = 0.0f;
    #pragma unroll
    for (int k = 0; k < 10; ++k) wmem[k] = 0.0f;
    #pragma unroll
    for (int s = 0; s < 8; ++s) {
        const float* rx = &g_xall[(size_t)(1024 + n * 8 + s) * 12];
        #pragma unroll
        for (int h = 0; h < 12; ++h) wdiff[h] += d[s] * (x[h] - rx[h]);
        const float* mr = mem + (size_t)refs[n * 8 + s] * 10;
        #pragma unroll
        for (int k = 0; k < 10; ++k) wmem[k] += d[s] * mr[k];
    }
    const float* gr = &g_grad[(size_t)n * 120];
    #pragma unroll
    for (int c = 0; c < 10; ++c) {
        float a = bm[c];
        #pragma unroll
        for (int k = 0; k < 10; ++k) a += wmem[k] * Wm[c * 10 + k];
        #pragma unroll
        for (int h = 0; h < 12; ++h) a += wdiff[h] * gr[h * 10 + c];
        out[(size_t)n * 10 + c] = a;
    }
}

extern "C" void kernel_launch(void* const* d_in, const int* in_sizes, int n_in,
                              void* d_out, int out_size, void* d_ws, size_t ws_size,
                              hipStream_t stream) {
    const float* img   = (const float*)d_in[0];
    const float* train = (const float*)d_in[1];
    const float* mem   = (const float*)d_in[2];
    const float* w1    = (const float*)d_in[3];
    const float* b1    = (const float*)d_in[4];
    const float* w2    = (const float*)d_in[5];
    const float* b2    = (const float*)d_in[6];
    const float* Wf    = (const float*)d_in[7];
    const float* bf    = (const float*)d_in[8];
    const float* Wg    = (const float*)d_in[9];
    const float* bg    = (const float*)d_in[10];
    const float* Wm    = (const float*)d_in[11];
    const float* bm    = (const float*)d_in[12];
    const int*   refs  = (const int*)d_in[14];
    float* out = (float*)d_out;

    lenet_kernel<<<9216, 256, 0, stream>>>(img, train, refs, w1, b1, w2, b2);
    xall_kernel<<<36, 256, 0, stream>>>(Wf, bf);
    grad_kernel<<<64, 64, 0, stream>>>(Wg, bg);
    combine_kernel<<<16, 64, 0, stream>>>(mem, Wm, bm, refs, out);
}